// Round 5
// baseline (129.299 us; speedup 1.0000x reference)
//
#include <hip/hip_runtime.h>

#define B_ 2
#define T_ 8
#define Z_ 20
#define Y_ 64
#define X_ 64
#define C_ 2
#define F1_ 32
#define F_ 32

constexpr int NPTS = B_*T_*Z_*Y_*X_;   // 1,310,720
constexpr int ZYX  = Z_*Y_*X_;         // 81,920

using bf8   = __attribute__((ext_vector_type(8))) short;
using f32x4 = __attribute__((ext_vector_type(4))) float;

__device__ inline unsigned short f2bf(float x) {   // RNE float->bf16
    unsigned u = __builtin_bit_cast(unsigned, x);
    return (unsigned short)((u + 0x7fff + ((u >> 16) & 1)) >> 16);
}
__device__ inline unsigned pk(float a, float b) {  // pack 2 bf16 into dword
    return (unsigned)f2bf(a) | ((unsigned)f2bf(b) << 16);
}

// ---------------------------------------------------------------------------
// Weight projection (unchanged, verified).
// ---------------------------------------------------------------------------
__global__ __launch_bounds__(64) void project_kernel(
    const float* __restrict__ wxr, const float* __restrict__ wxi,
    const float* __restrict__ wtr, const float* __restrict__ wti,
    float* __restrict__ psr, float* __restrict__ psi,
    float* __restrict__ otr, float* __restrict__ oti)
{
    const int bid  = blockIdx.x;
    const int lane = threadIdx.x;

    if (bid < F1_) {
        const int f = bid;
        float er = 0.f, ei = 0.f;
        if (lane < 54) { er = wxr[lane*F1_ + f]; ei = wxi[lane*F1_ + f]; }
        float sr = er, si = ei;
        #pragma unroll
        for (int o = 32; o >= 1; o >>= 1) { sr += __shfl_xor(sr, o); si += __shfl_xor(si, o); }
        const float mr = sr * (1.f/54.f), mi = si * (1.f/54.f);
        const float dr = er - mr, di = ei - mi;
        float sq = (lane < 54) ? (dr*dr + di*di) : 0.f;
        #pragma unroll
        for (int o = 32; o >= 1; o >>= 1) sq += __shfl_xor(sq, o);
        const float s = 1.f / fmaxf(sqrtf(sq), 1.f);
        if (lane < 54) { psr[lane*F1_ + f] = dr*s; psi[lane*F1_ + f] = di*s; }
    } else {
        const int f = bid - F1_;
        float er[2], ei[2];
        float sq = 0.f;
        #pragma unroll
        for (int k = 0; k < 2; ++k) {
            const int e = lane + k*64;
            if (e < 96) { er[k] = wtr[e*F_ + f]; ei[k] = wti[e*F_ + f]; sq += er[k]*er[k] + ei[k]*ei[k]; }
            else        { er[k] = 0.f;  ei[k] = 0.f; }
        }
        #pragma unroll
        for (int o = 32; o >= 1; o >>= 1) sq += __shfl_xor(sq, o);
        const float s = 1.f / fmaxf(sqrtf(sq), 1.f);
        #pragma unroll
        for (int k = 0; k < 2; ++k) {
            const int e = lane + k*64;
            if (e < 96) { otr[e*F_ + f] = er[k]*s; oti[e*F_ + f] = ei[k]*s; }
        }
    }
}

// ---------------------------------------------------------------------------
// Pack both weight sets into MFMA fragment order (bf16). Unchanged, verified.
// ---------------------------------------------------------------------------
__global__ __launch_bounds__(256) void pack_kernel(
    const float* __restrict__ psr, const float* __restrict__ psi,
    const float* __restrict__ ptr_, const float* __restrict__ pti,
    unsigned short* __restrict__ wsp, unsigned short* __restrict__ wp)
{
    const int g = blockIdx.x;
    if (g < 16) {
        for (int o = g*512 + threadIdx.x; o < (g+1)*512; o += 256) {
            const int j  = o & 7;
            const int l  = (o >> 3) & 63;
            const int gg = o >> 9;
            const int kb = gg & 3, ct = gg >> 2;
            const int k  = kb*32 + (l >> 4)*8 + j;
            const int n  = ct*16 + (l & 15);
            float v = 0.f;
            if (k < 108) {
                const int tap = k >> 2, q = k & 3, cin = q & 1, cp = q >> 1;
                const int f  = n & 31;
                const float wr = psr[(tap*2 + cin)*F1_ + f];
                const float wi = psi[(tap*2 + cin)*F1_ + f];
                v = (n < 32) ? (cp ? -wi : wr) : (cp ? wr : wi);
            }
            wsp[o] = f2bf(v);
        }
    } else {
        for (int o = (g-16)*512 + threadIdx.x; o < (g-15)*512; o += 256) {
            const int j  = o & 7;
            const int l  = (o >> 3) & 63;
            const int gg = o >> 9;          // ct*6 + kb
            const int kb = gg % 6, ct = gg / 6;
            const int k  = kb*32 + (l >> 4)*8 + j;
            const int n  = ct*16 + (l & 15);
            const int kt = k >> 6, f1 = (k >> 1) & 31, c = k & 1;
            const int f  = n & 31;
            const float wr = ptr_[(kt*F1_ + f1)*F_ + f];
            const float wi = pti[(kt*F1_ + f1)*F_ + f];
            const float v  = (n < 32) ? (c ? -wi : wr) : (c ? wr : wi);
            wp[o] = f2bf(v);
        }
    }
}

// ---------------------------------------------------------------------------
// Repack input to bf16: xb[p] = uint2{ r0|r1<<16, i0|i1<<16 }. Unchanged.
// ---------------------------------------------------------------------------
__global__ __launch_bounds__(256) void repack_kernel(
    const float* __restrict__ xr, const float* __restrict__ xi,
    uint2* __restrict__ xb)
{
    const int p = blockIdx.x*256 + threadIdx.x;
    const float2 vr = *reinterpret_cast<const float2*>(xr + (size_t)p*2);
    const float2 vi = *reinterpret_cast<const float2*>(xi + (size_t)p*2);
    uint2 v;
    v.x = (unsigned)f2bf(vr.x) | ((unsigned)f2bf(vr.y) << 16);
    v.y = (unsigned)f2bf(vi.x) | ((unsigned)f2bf(vi.y) << 16);
    xb[p] = v;
}

// ---------------------------------------------------------------------------
// Fused kernel, all-register version. Both GEMMs use swapped MFMA operands
// (mfma(W,X) = (X*W)^T with byte-identical fragments), so the spatial result
// lands per-lane exactly in temporal-B-fragment layout: no LDS ring at all.
// Slices live in a 3-deep register ring (2 bf8 each). Output: lane owns 4
// consecutive f -> 4 global_store_dwordx4 per EMIT.
// ---------------------------------------------------------------------------
__global__ __launch_bounds__(256) void fused_kernel(
    const uint2* __restrict__ xb,
    const unsigned short* __restrict__ wsp,
    const unsigned short* __restrict__ wp,
    float* __restrict__ yr, float* __restrict__ yi)
{
    const int tid  = threadIdx.x;
    const int lane = tid & 63;
    const int wid  = tid >> 6;
    const int lx   = lane & 15;
    const int lg   = lane >> 4;

    const int bq = blockIdx.x;          // b*Z*Y + z*Y + y
    const int y  = bq & 63;
    const int z  = (bq >> 6) % Z_;
    const int b  = bq / (64*Z_);
    const int x0 = wid * 16;

    // ---- weight fragments (same bytes as round 4; used as A-operand now) ----
    bf8 wsf[4][4];
    const bf8* w8 = reinterpret_cast<const bf8*>(wsp);
    #pragma unroll
    for (int ct = 0; ct < 4; ++ct)
        #pragma unroll
        for (int kb = 0; kb < 4; ++kb)
            wsf[ct][kb] = w8[(ct*4 + kb)*64 + lane];

    bf8 wtf[4][6];
    const bf8* wp8 = reinterpret_cast<const bf8*>(wp);
    #pragma unroll
    for (int ct = 0; ct < 4; ++ct)
        #pragma unroll
        for (int kb = 0; kb < 6; ++kb)
            wtf[ct][kb] = wp8[(ct*6 + kb)*64 + lane];

    // ---- per-lane input-gather offsets (reflect pad clamps hoisted) ----
    int off[4][2];
    #pragma unroll
    for (int kb = 0; kb < 4; ++kb)
        #pragma unroll
        for (int s = 0; s < 2; ++s) {
            int ta = kb*8 + lg*2 + s; if (ta > 26) ta = 26;   // k>=108: B is 0
            const int dz = ta/9, dyx = ta - dz*9, dy = dyx/3, dx = dyx - dy*3;
            int zz = z + dz - 1;      zz = zz < 0 ? 0 : (zz >= Z_ ? Z_-1 : zz);
            int yy = y + dy - 1;      yy = yy < 0 ? 0 : (yy >= Y_ ? Y_-1 : yy);
            int xx = x0 + lx + dx - 1; xx = xx < 0 ? 0 : (xx >= X_ ? X_-1 : xx);
            off[kb][s] = (zz*Y_ + yy)*X_ + xx;
        }

    // per-lane global point index at t=0
    const size_t orow = (((size_t)b*T_)*Z_ + z)*(size_t)(Y_*X_) + (size_t)y*X_ + x0 + lx;

    uint4 sl_lo[3], sl_hi[3];

    // spatial slice t -> (lo,hi) register fragments (temporal-B layout)
    auto SPATIAL = [&](int t, uint4& lo, uint4& hi) {
        const uint2* xt = xb + (size_t)(b*T_ + t)*ZYX;
        bf8 af[4];
        #pragma unroll
        for (int kb = 0; kb < 4; ++kb) {
            const uint2 l2 = xt[off[kb][0]];
            const uint2 h2 = xt[off[kb][1]];
            af[kb] = __builtin_bit_cast(bf8, make_uint4(l2.x, l2.y, h2.x, h2.y));
        }
        f32x4 acc[4];
        #pragma unroll
        for (int ct = 0; ct < 4; ++ct) acc[ct] = (f32x4){0.f,0.f,0.f,0.f};
        #pragma unroll
        for (int ct = 0; ct < 4; ++ct)
            #pragma unroll
            for (int kb = 0; kb < 4; ++kb)
                acc[ct] = __builtin_amdgcn_mfma_f32_16x16x32_bf16(
                              wsf[ct][kb], af[kb], acc[ct], 0, 0, 0);
        // acc[ct][j] = s_group[f1 = (ct&1)*16 + lg*4 + j][point = lx]
        lo = make_uint4(pk(acc[0][0],acc[2][0]), pk(acc[0][1],acc[2][1]),
                        pk(acc[0][2],acc[2][2]), pk(acc[0][3],acc[2][3]));
        hi = make_uint4(pk(acc[1][0],acc[3][0]), pk(acc[1][1],acc[3][1]),
                        pk(acc[1][2],acc[3][2]), pk(acc[1][3],acc[3][3]));
    };

    // temporal MFMA from 3 slices (kt order a,b,c) -> y(tout)
    auto EMIT = [&](const uint4& alo, const uint4& ahi,
                    const uint4& blo, const uint4& bhi,
                    const uint4& clo, const uint4& chi, int tout) {
        bf8 fr[6];
        fr[0] = __builtin_bit_cast(bf8, alo); fr[1] = __builtin_bit_cast(bf8, ahi);
        fr[2] = __builtin_bit_cast(bf8, blo); fr[3] = __builtin_bit_cast(bf8, bhi);
        fr[4] = __builtin_bit_cast(bf8, clo); fr[5] = __builtin_bit_cast(bf8, chi);
        f32x4 acc[4];
        #pragma unroll
        for (int ct = 0; ct < 4; ++ct) acc[ct] = (f32x4){0.f,0.f,0.f,0.f};
        #pragma unroll
        for (int ct = 0; ct < 4; ++ct)
            #pragma unroll
            for (int kb = 0; kb < 6; ++kb)
                acc[ct] = __builtin_amdgcn_mfma_f32_16x16x32_bf16(
                              wtf[ct][kb], fr[kb], acc[ct], 0, 0, 0);
        // acc[ct][j] = y_group[f = (ct&1)*16 + lg*4 + j][point = lx]
        const size_t p = orow + (size_t)tout * ZYX;
        #pragma unroll
        for (int ct = 0; ct < 4; ++ct) {
            float* outp = (ct < 2) ? yr : yi;
            *reinterpret_cast<f32x4*>(outp + p*F_ + (ct & 1)*16 + lg*4) = acc[ct];
        }
    };

    // t-loop fully unrolled; slice phase = t%3
    SPATIAL(0, sl_lo[0], sl_hi[0]);
    SPATIAL(1, sl_lo[1], sl_hi[1]);
    EMIT(sl_lo[0],sl_hi[0], sl_lo[0],sl_hi[0], sl_lo[1],sl_hi[1], 0);  // (0,0,1)
    SPATIAL(2, sl_lo[2], sl_hi[2]);
    EMIT(sl_lo[0],sl_hi[0], sl_lo[1],sl_hi[1], sl_lo[2],sl_hi[2], 1);  // (0,1,2)
    SPATIAL(3, sl_lo[0], sl_hi[0]);
    EMIT(sl_lo[1],sl_hi[1], sl_lo[2],sl_hi[2], sl_lo[0],sl_hi[0], 2);  // (1,2,3)
    SPATIAL(4, sl_lo[1], sl_hi[1]);
    EMIT(sl_lo[2],sl_hi[2], sl_lo[0],sl_hi[0], sl_lo[1],sl_hi[1], 3);  // (2,3,4)
    SPATIAL(5, sl_lo[2], sl_hi[2]);
    EMIT(sl_lo[0],sl_hi[0], sl_lo[1],sl_hi[1], sl_lo[2],sl_hi[2], 4);  // (3,4,5)
    SPATIAL(6, sl_lo[0], sl_hi[0]);
    EMIT(sl_lo[1],sl_hi[1], sl_lo[2],sl_hi[2], sl_lo[0],sl_hi[0], 5);  // (4,5,6)
    SPATIAL(7, sl_lo[1], sl_hi[1]);
    EMIT(sl_lo[2],sl_hi[2], sl_lo[0],sl_hi[0], sl_lo[1],sl_hi[1], 6);  // (5,6,7)
    EMIT(sl_lo[0],sl_hi[0], sl_lo[1],sl_hi[1], sl_lo[1],sl_hi[1], 7);  // (6,7,7)
}

extern "C" void kernel_launch(void* const* d_in, const int* in_sizes, int n_in,
                              void* d_out, int out_size, void* d_ws, size_t ws_size,
                              hipStream_t stream)
{
    const float* xr  = (const float*)d_in[0];
    const float* xi  = (const float*)d_in[1];
    const float* wxr = (const float*)d_in[2];
    const float* wxi = (const float*)d_in[3];
    const float* wtr = (const float*)d_in[4];
    const float* wti = (const float*)d_in[5];

    float* ws   = (float*)d_ws;
    float* psr  = ws;                                    // 1728
    float* psi  = ws + 2048;                             // 1728
    float* ptr_ = ws + 4096;                             // 3072
    float* pti  = ws + 8192;                             // 3072
    unsigned short* wsp = (unsigned short*)(ws + 12288); // 8192 ushorts (16KB)
    unsigned short* wp  = (unsigned short*)(ws + 16384); // 12288 ushorts (24KB)
    uint2* xb           = (uint2*)(ws + 32768);          // NPTS uint2 (10.5MB)

    float* yr = (float*)d_out;
    float* yi = yr + (size_t)NPTS * F_;

    hipLaunchKernelGGL(project_kernel, dim3(64), dim3(64), 0, stream,
                       wxr, wxi, wtr, wti, psr, psi, ptr_, pti);
    hipLaunchKernelGGL(pack_kernel, dim3(40), dim3(256), 0, stream,
                       psr, psi, ptr_, pti, wsp, wp);
    hipLaunchKernelGGL(repack_kernel, dim3(NPTS/256), dim3(256), 0, stream,
                       xr, xi, xb);
    hipLaunchKernelGGL(fused_kernel, dim3(B_*Z_*Y_), dim3(256), 0, stream,
                       xb, wsp, wp, yr, yi);
}

// Round 6
// 104.844 us; speedup vs baseline: 1.2333x; 1.2333x over previous
//
#include <hip/hip_runtime.h>

#define B_ 2
#define T_ 8
#define Z_ 20
#define Y_ 64
#define X_ 64
#define C_ 2
#define F1_ 32
#define F_ 32

constexpr int NPTS = B_*T_*Z_*Y_*X_;   // 1,310,720
constexpr int ZYX  = Z_*Y_*X_;         // 81,920

constexpr int RING_STRIDE = 36;            // dwords/row (16B-aligned rows)
constexpr int SLOT_DW     = 16*RING_STRIDE;// 576 dwords per ring slot

using bf8   = __attribute__((ext_vector_type(8))) short;
using f32x4 = __attribute__((ext_vector_type(4))) float;

__device__ inline unsigned short f2bf(float x) {   // RNE float->bf16
    unsigned u = __builtin_bit_cast(unsigned, x);
    return (unsigned short)((u + 0x7fff + ((u >> 16) & 1)) >> 16);
}
__device__ inline unsigned pk(float a, float b) {  // pack 2 bf16 into dword
    return (unsigned)f2bf(a) | ((unsigned)f2bf(b) << 16);
}

// ---------------------------------------------------------------------------
// Weight projection (unchanged, verified).
// ---------------------------------------------------------------------------
__global__ __launch_bounds__(64) void project_kernel(
    const float* __restrict__ wxr, const float* __restrict__ wxi,
    const float* __restrict__ wtr, const float* __restrict__ wti,
    float* __restrict__ psr, float* __restrict__ psi,
    float* __restrict__ otr, float* __restrict__ oti)
{
    const int bid  = blockIdx.x;
    const int lane = threadIdx.x;

    if (bid < F1_) {
        const int f = bid;
        float er = 0.f, ei = 0.f;
        if (lane < 54) { er = wxr[lane*F1_ + f]; ei = wxi[lane*F1_ + f]; }
        float sr = er, si = ei;
        #pragma unroll
        for (int o = 32; o >= 1; o >>= 1) { sr += __shfl_xor(sr, o); si += __shfl_xor(si, o); }
        const float mr = sr * (1.f/54.f), mi = si * (1.f/54.f);
        const float dr = er - mr, di = ei - mi;
        float sq = (lane < 54) ? (dr*dr + di*di) : 0.f;
        #pragma unroll
        for (int o = 32; o >= 1; o >>= 1) sq += __shfl_xor(sq, o);
        const float s = 1.f / fmaxf(sqrtf(sq), 1.f);
        if (lane < 54) { psr[lane*F1_ + f] = dr*s; psi[lane*F1_ + f] = di*s; }
    } else {
        const int f = bid - F1_;
        float er[2], ei[2];
        float sq = 0.f;
        #pragma unroll
        for (int k = 0; k < 2; ++k) {
            const int e = lane + k*64;
            if (e < 96) { er[k] = wtr[e*F_ + f]; ei[k] = wti[e*F_ + f]; sq += er[k]*er[k] + ei[k]*ei[k]; }
            else        { er[k] = 0.f;  ei[k] = 0.f; }
        }
        #pragma unroll
        for (int o = 32; o >= 1; o >>= 1) sq += __shfl_xor(sq, o);
        const float s = 1.f / fmaxf(sqrtf(sq), 1.f);
        #pragma unroll
        for (int k = 0; k < 2; ++k) {
            const int e = lane + k*64;
            if (e < 96) { otr[e*F_ + f] = er[k]*s; oti[e*F_ + f] = ei[k]*s; }
        }
    }
}

// ---------------------------------------------------------------------------
// Pack both weight sets into MFMA fragment order (bf16). Unchanged, verified.
// ---------------------------------------------------------------------------
__global__ __launch_bounds__(256) void pack_kernel(
    const float* __restrict__ psr, const float* __restrict__ psi,
    const float* __restrict__ ptr_, const float* __restrict__ pti,
    unsigned short* __restrict__ wsp, unsigned short* __restrict__ wp)
{
    const int g = blockIdx.x;
    if (g < 16) {
        for (int o = g*512 + threadIdx.x; o < (g+1)*512; o += 256) {
            const int j  = o & 7;
            const int l  = (o >> 3) & 63;
            const int gg = o >> 9;
            const int kb = gg & 3, ct = gg >> 2;
            const int k  = kb*32 + (l >> 4)*8 + j;
            const int n  = ct*16 + (l & 15);
            float v = 0.f;
            if (k < 108) {
                const int tap = k >> 2, q = k & 3, cin = q & 1, cp = q >> 1;
                const int f  = n & 31;
                const float wr = psr[(tap*2 + cin)*F1_ + f];
                const float wi = psi[(tap*2 + cin)*F1_ + f];
                v = (n < 32) ? (cp ? -wi : wr) : (cp ? wr : wi);
            }
            wsp[o] = f2bf(v);
        }
    } else {
        for (int o = (g-16)*512 + threadIdx.x; o < (g-15)*512; o += 256) {
            const int j  = o & 7;
            const int l  = (o >> 3) & 63;
            const int gg = o >> 9;          // ct*6 + kb
            const int kb = gg % 6, ct = gg / 6;
            const int k  = kb*32 + (l >> 4)*8 + j;
            const int n  = ct*16 + (l & 15);
            const int kt = k >> 6, f1 = (k >> 1) & 31, c = k & 1;
            const int f  = n & 31;
            const float wr = ptr_[(kt*F1_ + f1)*F_ + f];
            const float wi = pti[(kt*F1_ + f1)*F_ + f];
            const float v  = (n < 32) ? (c ? -wi : wr) : (c ? wr : wi);
            wp[o] = f2bf(v);
        }
    }
}

// ---------------------------------------------------------------------------
// Repack input to bf16: xb[p] = uint2{ r0|r1<<16, i0|i1<<16 }. Unchanged.
// ---------------------------------------------------------------------------
__global__ __launch_bounds__(256) void repack_kernel(
    const float* __restrict__ xr, const float* __restrict__ xi,
    uint2* __restrict__ xb)
{
    const int p = blockIdx.x*256 + threadIdx.x;
    const float2 vr = *reinterpret_cast<const float2*>(xr + (size_t)p*2);
    const float2 vi = *reinterpret_cast<const float2*>(xi + (size_t)p*2);
    uint2 v;
    v.x = (unsigned)f2bf(vr.x) | ((unsigned)f2bf(vr.y) << 16);
    v.y = (unsigned)f2bf(vi.x) | ((unsigned)f2bf(vi.y) << 16);
    xb[p] = v;
}

// ---------------------------------------------------------------------------
// Fused kernel, hybrid version. Both GEMMs use swapped MFMA operands
// (W as A-operand; fragments byte-identical to the verified packs).
// - Swapped spatial => lane holds 4 consecutive f1 per point => slice write
//   is 2x ds_write_b128 into a wave-private LDS ring (row-major [point][f1],
//   stride 36 dwords, b128-aligned, conflict-free).
// - Only the CURRENT slice stays in registers (kt=2 operand); kt=0/1 come
//   from the ring via 4x ds_read_b128 (round-4-verified addressing).
// - Swapped temporal => epilogue is 4x global_store_dwordx4.
// ---------------------------------------------------------------------------
__global__ __launch_bounds__(256) void fused_kernel(
    const uint2* __restrict__ xb,
    const unsigned short* __restrict__ wsp,
    const unsigned short* __restrict__ wp,
    float* __restrict__ yr, float* __restrict__ yi)
{
    __shared__ uint4 ring4[4*3*SLOT_DW/4];   // 27.6 KB
    unsigned* ring = reinterpret_cast<unsigned*>(ring4);

    const int tid  = threadIdx.x;
    const int lane = tid & 63;
    const int wid  = tid >> 6;
    const int lx   = lane & 15;
    const int lg   = lane >> 4;

    const int bq = blockIdx.x;          // b*Z*Y + z*Y + y
    const int y  = bq & 63;
    const int z  = (bq >> 6) % Z_;
    const int b  = bq / (64*Z_);
    const int x0 = wid * 16;

    // ---- weight fragments (used as A-operands) ----
    bf8 wsf[4][4];
    const bf8* w8 = reinterpret_cast<const bf8*>(wsp);
    #pragma unroll
    for (int ct = 0; ct < 4; ++ct)
        #pragma unroll
        for (int kb = 0; kb < 4; ++kb)
            wsf[ct][kb] = w8[(ct*4 + kb)*64 + lane];

    bf8 wtf[4][6];
    const bf8* wp8 = reinterpret_cast<const bf8*>(wp);
    #pragma unroll
    for (int ct = 0; ct < 4; ++ct)
        #pragma unroll
        for (int kb = 0; kb < 6; ++kb)
            wtf[ct][kb] = wp8[(ct*6 + kb)*64 + lane];

    // ---- per-lane input-gather offsets (reflect pad clamps hoisted) ----
    int off[4][2];
    #pragma unroll
    for (int kb = 0; kb < 4; ++kb)
        #pragma unroll
        for (int s = 0; s < 2; ++s) {
            int ta = kb*8 + lg*2 + s; if (ta > 26) ta = 26;   // k>=108: B is 0
            const int dz = ta/9, dyx = ta - dz*9, dy = dyx/3, dx = dyx - dy*3;
            int zz = z + dz - 1;      zz = zz < 0 ? 0 : (zz >= Z_ ? Z_-1 : zz);
            int yy = y + dy - 1;      yy = yy < 0 ? 0 : (yy >= Y_ ? Y_-1 : yy);
            int xx = x0 + lx + dx - 1; xx = xx < 0 ? 0 : (xx >= X_ ? X_-1 : xx);
            off[kb][s] = (zz*Y_ + yy)*X_ + xx;
        }

    unsigned* myring  = ring + wid*3*SLOT_DW;
    const int  rbase  = lx*RING_STRIDE + lg*4;   // dword offset within a slot
    const size_t orow = (((size_t)b*T_)*Z_ + z)*(size_t)(Y_*X_) + (size_t)y*X_ + x0 + lx;

    uint4 cur_lo, cur_hi;                        // current slice fragments

    // spatial slice t -> cur_lo/cur_hi (temporal-B-fragment layout)
    auto SPATIAL = [&](int t) {
        const uint2* xt = xb + (size_t)(b*T_ + t)*ZYX;
        bf8 af[4];
        #pragma unroll
        for (int kb = 0; kb < 4; ++kb) {
            const uint2 l2 = xt[off[kb][0]];
            const uint2 h2 = xt[off[kb][1]];
            af[kb] = __builtin_bit_cast(bf8, make_uint4(l2.x, l2.y, h2.x, h2.y));
        }
        f32x4 acc[4];
        #pragma unroll
        for (int ct = 0; ct < 4; ++ct) acc[ct] = (f32x4){0.f,0.f,0.f,0.f};
        #pragma unroll
        for (int ct = 0; ct < 4; ++ct)
            #pragma unroll
            for (int kb = 0; kb < 4; ++kb)
                acc[ct] = __builtin_amdgcn_mfma_f32_16x16x32_bf16(
                              wsf[ct][kb], af[kb], acc[ct], 0, 0, 0);
        // D[row = f1-within-group = lg*4+j][col = point = lx]
        cur_lo = make_uint4(pk(acc[0][0],acc[2][0]), pk(acc[0][1],acc[2][1]),
                            pk(acc[0][2],acc[2][2]), pk(acc[0][3],acc[2][3]));
        cur_hi = make_uint4(pk(acc[1][0],acc[3][0]), pk(acc[1][1],acc[3][1]),
                            pk(acc[1][2],acc[3][2]), pk(acc[1][3],acc[3][3]));
    };

    auto WRITE = [&](int t) {
        unsigned* s = myring + (t % 3)*SLOT_DW + rbase;
        *reinterpret_cast<uint4*>(s)      = cur_lo;
        *reinterpret_cast<uint4*>(s + 16) = cur_hi;
    };

    // y(tout) from kt0 = slice sa (LDS), kt1 = slice sb (LDS), kt2 = cur (regs)
    auto EMIT = [&](int sa, int sb, int tout) {
        const unsigned* pa = myring + (sa % 3)*SLOT_DW + rbase;
        const unsigned* pb = myring + (sb % 3)*SLOT_DW + rbase;
        bf8 fr[6];
        fr[0] = __builtin_bit_cast(bf8, *reinterpret_cast<const uint4*>(pa));
        fr[1] = __builtin_bit_cast(bf8, *reinterpret_cast<const uint4*>(pa + 16));
        fr[2] = __builtin_bit_cast(bf8, *reinterpret_cast<const uint4*>(pb));
        fr[3] = __builtin_bit_cast(bf8, *reinterpret_cast<const uint4*>(pb + 16));
        fr[4] = __builtin_bit_cast(bf8, cur_lo);
        fr[5] = __builtin_bit_cast(bf8, cur_hi);
        f32x4 acc[4];
        #pragma unroll
        for (int ct = 0; ct < 4; ++ct) acc[ct] = (f32x4){0.f,0.f,0.f,0.f};
        #pragma unroll
        for (int ct = 0; ct < 4; ++ct)
            #pragma unroll
            for (int kb = 0; kb < 6; ++kb)
                acc[ct] = __builtin_amdgcn_mfma_f32_16x16x32_bf16(
                              wtf[ct][kb], fr[kb], acc[ct], 0, 0, 0);
        // D[row = f-within-group = lg*4+j][col = point = lx]
        const size_t p = orow + (size_t)tout * ZYX;
        #pragma unroll
        for (int ct = 0; ct < 4; ++ct) {
            float* outp = (ct < 2) ? yr : yi;
            *reinterpret_cast<f32x4*>(outp + p*F_ + (ct & 1)*16 + lg*4) = acc[ct];
        }
    };

    SPATIAL(0);
    WRITE(0);
    #pragma unroll 1
    for (int t = 1; t < T_; ++t) {
        SPATIAL(t);                       // cur = s(t)
        EMIT(t-2 < 0 ? 0 : t-2, t-1, t-1);
        WRITE(t);                         // slot t%3 != slots read above
    }
    EMIT(T_-2, T_-1, T_-1);               // y(7) = (s6, s7, s7); cur = s(7)
}

extern "C" void kernel_launch(void* const* d_in, const int* in_sizes, int n_in,
                              void* d_out, int out_size, void* d_ws, size_t ws_size,
                              hipStream_t stream)
{
    const float* xr  = (const float*)d_in[0];
    const float* xi  = (const float*)d_in[1];
    const float* wxr = (const float*)d_in[2];
    const float* wxi = (const float*)d_in[3];
    const float* wtr = (const float*)d_in[4];
    const float* wti = (const float*)d_in[5];

    float* ws   = (float*)d_ws;
    float* psr  = ws;                                    // 1728
    float* psi  = ws + 2048;                             // 1728
    float* ptr_ = ws + 4096;                             // 3072
    float* pti  = ws + 8192;                             // 3072
    unsigned short* wsp = (unsigned short*)(ws + 12288); // 8192 ushorts (16KB)
    unsigned short* wp  = (unsigned short*)(ws + 16384); // 12288 ushorts (24KB)
    uint2* xb           = (uint2*)(ws + 32768);          // NPTS uint2 (10.5MB)

    float* yr = (float*)d_out;
    float* yi = yr + (size_t)NPTS * F_;

    hipLaunchKernelGGL(project_kernel, dim3(64), dim3(64), 0, stream,
                       wxr, wxi, wtr, wti, psr, psi, ptr_, pti);
    hipLaunchKernelGGL(pack_kernel, dim3(40), dim3(256), 0, stream,
                       psr, psi, ptr_, pti, wsp, wp);
    hipLaunchKernelGGL(repack_kernel, dim3(NPTS/256), dim3(256), 0, stream,
                       xr, xi, xb);
    hipLaunchKernelGGL(fused_kernel, dim3(B_*Z_*Y_), dim3(256), 0, stream,
                       xb, wsp, wp, yr, yi);
}

// Round 7
// 99.240 us; speedup vs baseline: 1.3029x; 1.0565x over previous
//
#include <hip/hip_runtime.h>

#define B_ 2
#define T_ 8
#define Z_ 20
#define Y_ 64
#define X_ 64
#define C_ 2
#define F1_ 32
#define F_ 32

constexpr int NPTS = B_*T_*Z_*Y_*X_;   // 1,310,720
constexpr int ZYX  = Z_*Y_*X_;         // 81,920

constexpr int RING_STRIDE = 36;            // dwords/row (16B-aligned rows)
constexpr int SLOT_DW     = 16*RING_STRIDE;// 576 dwords per ring slot

using bf8   = __attribute__((ext_vector_type(8))) short;
using f32x4 = __attribute__((ext_vector_type(4))) float;

__device__ inline unsigned short f2bf(float x) {   // RNE float->bf16
    unsigned u = __builtin_bit_cast(unsigned, x);
    return (unsigned short)((u + 0x7fff + ((u >> 16) & 1)) >> 16);
}
__device__ inline unsigned pk(float a, float b) {  // pack 2 bf16 into dword
    return (unsigned)f2bf(a) | ((unsigned)f2bf(b) << 16);
}

// ---------------------------------------------------------------------------
// Weight projection (unchanged, verified).
// ---------------------------------------------------------------------------
__global__ __launch_bounds__(64) void project_kernel(
    const float* __restrict__ wxr, const float* __restrict__ wxi,
    const float* __restrict__ wtr, const float* __restrict__ wti,
    float* __restrict__ psr, float* __restrict__ psi,
    float* __restrict__ otr, float* __restrict__ oti)
{
    const int bid  = blockIdx.x;
    const int lane = threadIdx.x;

    if (bid < F1_) {
        const int f = bid;
        float er = 0.f, ei = 0.f;
        if (lane < 54) { er = wxr[lane*F1_ + f]; ei = wxi[lane*F1_ + f]; }
        float sr = er, si = ei;
        #pragma unroll
        for (int o = 32; o >= 1; o >>= 1) { sr += __shfl_xor(sr, o); si += __shfl_xor(si, o); }
        const float mr = sr * (1.f/54.f), mi = si * (1.f/54.f);
        const float dr = er - mr, di = ei - mi;
        float sq = (lane < 54) ? (dr*dr + di*di) : 0.f;
        #pragma unroll
        for (int o = 32; o >= 1; o >>= 1) sq += __shfl_xor(sq, o);
        const float s = 1.f / fmaxf(sqrtf(sq), 1.f);
        if (lane < 54) { psr[lane*F1_ + f] = dr*s; psi[lane*F1_ + f] = di*s; }
    } else {
        const int f = bid - F1_;
        float er[2], ei[2];
        float sq = 0.f;
        #pragma unroll
        for (int k = 0; k < 2; ++k) {
            const int e = lane + k*64;
            if (e < 96) { er[k] = wtr[e*F_ + f]; ei[k] = wti[e*F_ + f]; sq += er[k]*er[k] + ei[k]*ei[k]; }
            else        { er[k] = 0.f;  ei[k] = 0.f; }
        }
        #pragma unroll
        for (int o = 32; o >= 1; o >>= 1) sq += __shfl_xor(sq, o);
        const float s = 1.f / fmaxf(sqrtf(sq), 1.f);
        #pragma unroll
        for (int k = 0; k < 2; ++k) {
            const int e = lane + k*64;
            if (e < 96) { otr[e*F_ + f] = er[k]*s; oti[e*F_ + f] = ei[k]*s; }
        }
    }
}

// ---------------------------------------------------------------------------
// Pack both weight sets into MFMA fragment order (bf16). Unchanged, verified.
// ---------------------------------------------------------------------------
__global__ __launch_bounds__(256) void pack_kernel(
    const float* __restrict__ psr, const float* __restrict__ psi,
    const float* __restrict__ ptr_, const float* __restrict__ pti,
    unsigned short* __restrict__ wsp, unsigned short* __restrict__ wp)
{
    const int g = blockIdx.x;
    if (g < 16) {
        for (int o = g*512 + threadIdx.x; o < (g+1)*512; o += 256) {
            const int j  = o & 7;
            const int l  = (o >> 3) & 63;
            const int gg = o >> 9;
            const int kb = gg & 3, ct = gg >> 2;
            const int k  = kb*32 + (l >> 4)*8 + j;
            const int n  = ct*16 + (l & 15);
            float v = 0.f;
            if (k < 108) {
                const int tap = k >> 2, q = k & 3, cin = q & 1, cp = q >> 1;
                const int f  = n & 31;
                const float wr = psr[(tap*2 + cin)*F1_ + f];
                const float wi = psi[(tap*2 + cin)*F1_ + f];
                v = (n < 32) ? (cp ? -wi : wr) : (cp ? wr : wi);
            }
            wsp[o] = f2bf(v);
        }
    } else {
        for (int o = (g-16)*512 + threadIdx.x; o < (g-15)*512; o += 256) {
            const int j  = o & 7;
            const int l  = (o >> 3) & 63;
            const int gg = o >> 9;          // ct*6 + kb
            const int kb = gg % 6, ct = gg / 6;
            const int k  = kb*32 + (l >> 4)*8 + j;
            const int n  = ct*16 + (l & 15);
            const int kt = k >> 6, f1 = (k >> 1) & 31, c = k & 1;
            const int f  = n & 31;
            const float wr = ptr_[(kt*F1_ + f1)*F_ + f];
            const float wi = pti[(kt*F1_ + f1)*F_ + f];
            const float v  = (n < 32) ? (c ? -wi : wr) : (c ? wr : wi);
            wp[o] = f2bf(v);
        }
    }
}

// ---------------------------------------------------------------------------
// Repack input to bf16: xb[p] = uint2{ r0|r1<<16, i0|i1<<16 }. Unchanged.
// ---------------------------------------------------------------------------
__global__ __launch_bounds__(256) void repack_kernel(
    const float* __restrict__ xr, const float* __restrict__ xi,
    uint2* __restrict__ xb)
{
    const int p = blockIdx.x*256 + threadIdx.x;
    const float2 vr = *reinterpret_cast<const float2*>(xr + (size_t)p*2);
    const float2 vi = *reinterpret_cast<const float2*>(xi + (size_t)p*2);
    uint2 v;
    v.x = (unsigned)f2bf(vr.x) | ((unsigned)f2bf(vr.y) << 16);
    v.y = (unsigned)f2bf(vi.x) | ((unsigned)f2bf(vi.y) << 16);
    xb[p] = v;
}

// ---------------------------------------------------------------------------
// Fused kernel, hybrid + prefetch version. Identical arithmetic to round 6;
// the only change: per-t input gathers are double-buffered in registers and
// issued one t AHEAD (T14 issue-early/consume-late), so L2/L3 gather latency
// hides under the previous step's EMIT MFMAs + stores.
// ---------------------------------------------------------------------------
__global__ __launch_bounds__(256, 2) void fused_kernel(
    const uint2* __restrict__ xb,
    const unsigned short* __restrict__ wsp,
    const unsigned short* __restrict__ wp,
    float* __restrict__ yr, float* __restrict__ yi)
{
    __shared__ uint4 ring4[4*3*SLOT_DW/4];   // 27.6 KB
    unsigned* ring = reinterpret_cast<unsigned*>(ring4);

    const int tid  = threadIdx.x;
    const int lane = tid & 63;
    const int wid  = tid >> 6;
    const int lx   = lane & 15;
    const int lg   = lane >> 4;

    const int bq = blockIdx.x;          // b*Z*Y + z*Y + y
    const int y  = bq & 63;
    const int z  = (bq >> 6) % Z_;
    const int b  = bq / (64*Z_);
    const int x0 = wid * 16;

    // ---- weight fragments (used as A-operands) ----
    bf8 wsf[4][4];
    const bf8* w8 = reinterpret_cast<const bf8*>(wsp);
    #pragma unroll
    for (int ct = 0; ct < 4; ++ct)
        #pragma unroll
        for (int kb = 0; kb < 4; ++kb)
            wsf[ct][kb] = w8[(ct*4 + kb)*64 + lane];

    bf8 wtf[4][6];
    const bf8* wp8 = reinterpret_cast<const bf8*>(wp);
    #pragma unroll
    for (int ct = 0; ct < 4; ++ct)
        #pragma unroll
        for (int kb = 0; kb < 6; ++kb)
            wtf[ct][kb] = wp8[(ct*6 + kb)*64 + lane];

    // ---- per-lane input-gather offsets (reflect pad clamps hoisted) ----
    int off[4][2];
    #pragma unroll
    for (int kb = 0; kb < 4; ++kb)
        #pragma unroll
        for (int s = 0; s < 2; ++s) {
            int ta = kb*8 + lg*2 + s; if (ta > 26) ta = 26;   // k>=108: B is 0
            const int dz = ta/9, dyx = ta - dz*9, dy = dyx/3, dx = dyx - dy*3;
            int zz = z + dz - 1;      zz = zz < 0 ? 0 : (zz >= Z_ ? Z_-1 : zz);
            int yy = y + dy - 1;      yy = yy < 0 ? 0 : (yy >= Y_ ? Y_-1 : yy);
            int xx = x0 + lx + dx - 1; xx = xx < 0 ? 0 : (xx >= X_ ? X_-1 : xx);
            off[kb][s] = (zz*Y_ + yy)*X_ + xx;
        }

    unsigned* myring  = ring + wid*3*SLOT_DW;
    const int  rbase  = lx*RING_STRIDE + lg*4;   // dword offset within a slot
    const size_t orow = (((size_t)b*T_)*Z_ + z)*(size_t)(Y_*X_) + (size_t)y*X_ + x0 + lx;

    uint4 cur_lo, cur_hi;                        // current slice fragments
    uint2 ga[8], gb[8];                          // double-buffered gathers

    auto LOADG = [&](uint2 (&g)[8], int t) {
        const uint2* xt = xb + (size_t)(b*T_ + t)*ZYX;
        #pragma unroll
        for (int kb = 0; kb < 4; ++kb) {
            g[kb*2+0] = xt[off[kb][0]];
            g[kb*2+1] = xt[off[kb][1]];
        }
    };

    // spatial MFMA from pre-gathered regs -> cur_lo/cur_hi (temporal-B layout)
    auto SPATIAL = [&](const uint2 (&g)[8]) {
        bf8 af[4];
        #pragma unroll
        for (int kb = 0; kb < 4; ++kb)
            af[kb] = __builtin_bit_cast(bf8,
                make_uint4(g[kb*2].x, g[kb*2].y, g[kb*2+1].x, g[kb*2+1].y));
        f32x4 acc[4];
        #pragma unroll
        for (int ct = 0; ct < 4; ++ct) acc[ct] = (f32x4){0.f,0.f,0.f,0.f};
        #pragma unroll
        for (int ct = 0; ct < 4; ++ct)
            #pragma unroll
            for (int kb = 0; kb < 4; ++kb)
                acc[ct] = __builtin_amdgcn_mfma_f32_16x16x32_bf16(
                              wsf[ct][kb], af[kb], acc[ct], 0, 0, 0);
        cur_lo = make_uint4(pk(acc[0][0],acc[2][0]), pk(acc[0][1],acc[2][1]),
                            pk(acc[0][2],acc[2][2]), pk(acc[0][3],acc[2][3]));
        cur_hi = make_uint4(pk(acc[1][0],acc[3][0]), pk(acc[1][1],acc[3][1]),
                            pk(acc[1][2],acc[3][2]), pk(acc[1][3],acc[3][3]));
    };

    auto WRITE = [&](int t) {
        unsigned* s = myring + (t % 3)*SLOT_DW + rbase;
        *reinterpret_cast<uint4*>(s)      = cur_lo;
        *reinterpret_cast<uint4*>(s + 16) = cur_hi;
    };

    // y(tout) from kt0 = slice sa (LDS), kt1 = slice sb (LDS), kt2 = cur (regs)
    auto EMIT = [&](int sa, int sb, int tout) {
        const unsigned* pa = myring + (sa % 3)*SLOT_DW + rbase;
        const unsigned* pb = myring + (sb % 3)*SLOT_DW + rbase;
        bf8 fr[6];
        fr[0] = __builtin_bit_cast(bf8, *reinterpret_cast<const uint4*>(pa));
        fr[1] = __builtin_bit_cast(bf8, *reinterpret_cast<const uint4*>(pa + 16));
        fr[2] = __builtin_bit_cast(bf8, *reinterpret_cast<const uint4*>(pb));
        fr[3] = __builtin_bit_cast(bf8, *reinterpret_cast<const uint4*>(pb + 16));
        fr[4] = __builtin_bit_cast(bf8, cur_lo);
        fr[5] = __builtin_bit_cast(bf8, cur_hi);
        f32x4 acc[4];
        #pragma unroll
        for (int ct = 0; ct < 4; ++ct) acc[ct] = (f32x4){0.f,0.f,0.f,0.f};
        #pragma unroll
        for (int ct = 0; ct < 4; ++ct)
            #pragma unroll
            for (int kb = 0; kb < 6; ++kb)
                acc[ct] = __builtin_amdgcn_mfma_f32_16x16x32_bf16(
                              wtf[ct][kb], fr[kb], acc[ct], 0, 0, 0);
        const size_t p = orow + (size_t)tout * ZYX;
        #pragma unroll
        for (int ct = 0; ct < 4; ++ct) {
            float* outp = (ct < 2) ? yr : yi;
            *reinterpret_cast<f32x4*>(outp + p*F_ + (ct & 1)*16 + lg*4) = acc[ct];
        }
    };

    // step t: prefetch t+1 into dst, compute s(t) from src, emit y(t-1), stash
    auto STEP = [&](int t, const uint2 (&src)[8], uint2 (&dst)[8], bool pf) {
        if (pf) LOADG(dst, t+1);               // issue-early: hides under MFMAs
        SPATIAL(src);
        EMIT(t-2 < 0 ? 0 : t-2, t-1, t-1);
        WRITE(t);
    };

    LOADG(ga, 0);
    LOADG(gb, 1);          // both tiles in flight before first compute
    SPATIAL(ga);
    WRITE(0);
    STEP(1, gb, ga, true);   // prefetch t=2
    STEP(2, ga, gb, true);   // prefetch t=3
    STEP(3, gb, ga, true);
    STEP(4, ga, gb, true);
    STEP(5, gb, ga, true);
    STEP(6, ga, gb, true);   // prefetch t=7
    STEP(7, gb, ga, false);
    EMIT(T_-2, T_-1, T_-1);  // y(7) = (s6, s7, s7); cur = s(7)
}

extern "C" void kernel_launch(void* const* d_in, const int* in_sizes, int n_in,
                              void* d_out, int out_size, void* d_ws, size_t ws_size,
                              hipStream_t stream)
{
    const float* xr  = (const float*)d_in[0];
    const float* xi  = (const float*)d_in[1];
    const float* wxr = (const float*)d_in[2];
    const float* wxi = (const float*)d_in[3];
    const float* wtr = (const float*)d_in[4];
    const float* wti = (const float*)d_in[5];

    float* ws   = (float*)d_ws;
    float* psr  = ws;                                    // 1728
    float* psi  = ws + 2048;                             // 1728
    float* ptr_ = ws + 4096;                             // 3072
    float* pti  = ws + 8192;                             // 3072
    unsigned short* wsp = (unsigned short*)(ws + 12288); // 8192 ushorts (16KB)
    unsigned short* wp  = (unsigned short*)(ws + 16384); // 12288 ushorts (24KB)
    uint2* xb           = (uint2*)(ws + 32768);          // NPTS uint2 (10.5MB)

    float* yr = (float*)d_out;
    float* yi = yr + (size_t)NPTS * F_;

    hipLaunchKernelGGL(project_kernel, dim3(64), dim3(64), 0, stream,
                       wxr, wxi, wtr, wti, psr, psi, ptr_, pti);
    hipLaunchKernelGGL(pack_kernel, dim3(40), dim3(256), 0, stream,
                       psr, psi, ptr_, pti, wsp, wp);
    hipLaunchKernelGGL(repack_kernel, dim3(NPTS/256), dim3(256), 0, stream,
                       xr, xi, xb);
    hipLaunchKernelGGL(fused_kernel, dim3(B_*Z_*Y_), dim3(256), 0, stream,
                       xb, wsp, wp, yr, yi);
}